// Round 1
// baseline (459.620 us; speedup 1.0000x reference)
//
#include <hip/hip_runtime.h>
#include <hip/hip_bf16.h>
#include <math.h>

#define DIM 2048
#define BATCH 16384

typedef __attribute__((ext_vector_type(8))) short short8;
typedef __attribute__((ext_vector_type(4))) float floatx4;
typedef unsigned short ushort_t;

__device__ __forceinline__ ushort_t f2bf(float f) {
    union { float f; unsigned u; } v; v.f = f;
    unsigned r = v.u + 0x7FFFu + ((v.u >> 16) & 1u);   // RNE
    return (ushort_t)(r >> 16);
}

// ---- band scale vector (length DIM) ----
__global__ void k_scale(const float* __restrict__ fw, const float* __restrict__ kp,
                        float* __restrict__ s) {
    int n = blockIdx.x * blockDim.x + threadIdx.x;
    if (n >= DIM) return;
    float kv = kp[0];
    float f = 1.0f;
    for (int i = 0; i < 30; ++i) {
        long s0 = (long)((double)i       * (double)(DIM - 1) / 30.0);
        long e0 = (long)((double)(i + 1) * (double)(DIM - 1) / 30.0);
        if (n >= s0 && n < e0) {
            if (e0 <= 30)
                f = 1.0f + fw[i] * kv * (1.0f - (float)i / 30.0f);
            else
                f = 1.0f - fw[i] * kv * (1.0f - (float)(i - 30) / 30.0f);
        }
    }
    s[n] = f;
}

// ---- DCT matrix + transpose, bf16, exact integer phase reduction ----
__global__ void k_gen_d(ushort_t* __restrict__ D, ushort_t* __restrict__ Dt) {
    int idx = blockIdx.x * blockDim.x + threadIdx.x;   // DIM*DIM
    int r = idx >> 11;
    int c = idx & (DIM - 1);
    const float w  = 7.6699039394282058e-4f;  // pi/4096
    const float s0 = 0.02209708691207961f;    // sqrt(1/2048)
    const float s1 = 0.03125f;                // sqrt(2/2048)
    int m1 = ((2 * c + 1) * r) & (4 * DIM - 1);   // D[r][c]: cos(pi*(c+.5)*r/N)
    int m2 = ((2 * r + 1) * c) & (4 * DIM - 1);   // Dt[r][c] = D[c][r]
    float v1 = cosf(w * (float)m1) * (r == 0 ? s0 : s1);
    float v2 = cosf(w * (float)m2) * (c == 0 ? s0 : s1);
    D[idx]  = f2bf(v1);
    Dt[idx] = f2bf(v2);
}

// ---- fp32 -> bf16 cast, 8 elems/thread ----
__global__ void k_cast8(const float* __restrict__ in, ushort_t* __restrict__ out, int n8) {
    int i = blockIdx.x * blockDim.x + threadIdx.x;
    if (i >= n8) return;
    const float4* p = reinterpret_cast<const float4*>(in) + 2 * (size_t)i;
    float4 a = p[0], b = p[1];
    short8 r;
    r[0] = (short)f2bf(a.x); r[1] = (short)f2bf(a.y);
    r[2] = (short)f2bf(a.z); r[3] = (short)f2bf(a.w);
    r[4] = (short)f2bf(b.x); r[5] = (short)f2bf(b.y);
    r[6] = (short)f2bf(b.z); r[7] = (short)f2bf(b.w);
    *reinterpret_cast<short8*>(out + 8 * (size_t)i) = r;
}

// ---- C = A @ B^T, A: MxK bf16 row-major, B: NxK bf16 row-major (m97 structure) ----
// EPI 0: *ep0[col] -> bf16 | 1: plain -> bf16 | 2: +ep0[col], relu -> bf16
// EPI 3: +bias (ep0 cols<N/2, ep1 cols>=N/2) -> fp32 split output (mu | logvar)
template<int TM, int TN, int EPI>
__global__ __launch_bounds__(256)
void gemm_bt(const ushort_t* __restrict__ A, const ushort_t* __restrict__ B,
             ushort_t* __restrict__ Cb, float* __restrict__ Cf,
             const float* __restrict__ ep0, const float* __restrict__ ep1,
             int M, int N, int K) {
    constexpr int BM = 32 * TM;
    constexpr int BN = 32 * TN;
    __shared__ __align__(16) ushort_t As[BM * 32];
    __shared__ __align__(16) ushort_t Bs[BN * 32];

    const int tid  = threadIdx.x;
    const int lane = tid & 63;
    const int wave = tid >> 6;
    const int wm   = wave >> 1;
    const int wn   = wave & 1;
    const int q    = lane >> 4;
    const int l16  = lane & 15;

    const int tilesN = N / BN;
    const int bm = (int)blockIdx.x / tilesN;
    const int bn = (int)blockIdx.x % tilesN;

    floatx4 acc[TM][TN];
    #pragma unroll
    for (int i = 0; i < TM; ++i)
        #pragma unroll
        for (int j = 0; j < TN; ++j)
            acc[i][j] = (floatx4){0.f, 0.f, 0.f, 0.f};

    const long aBase = (long)bm * BM * K;
    const long bBase = (long)bn * BN * K;

    for (int kt = 0; kt < K; kt += 32) {
        __syncthreads();
        #pragma unroll
        for (int i = 0; i < BM / 64; ++i) {
            int idx = tid + i * 256;
            int row = idx >> 2, seg = idx & 3;
            const ushort_t* g = A + aBase + (long)row * K + kt + seg * 8;
            __builtin_amdgcn_global_load_lds(
                (const __attribute__((address_space(1))) void*)g,
                (__attribute__((address_space(3))) void*)(As + idx * 8),
                16, 0, 0);
        }
        #pragma unroll
        for (int i = 0; i < BN / 64; ++i) {
            int idx = tid + i * 256;
            int row = idx >> 2, seg = idx & 3;
            const ushort_t* g = B + bBase + (long)row * K + kt + seg * 8;
            __builtin_amdgcn_global_load_lds(
                (const __attribute__((address_space(1))) void*)g,
                (__attribute__((address_space(3))) void*)(Bs + idx * 8),
                16, 0, 0);
        }
        __syncthreads();

        short8 af[TM], bfr[TN];
        #pragma unroll
        for (int t = 0; t < TM; ++t)
            af[t] = *reinterpret_cast<const short8*>(
                &As[(wm * TM * 16 + t * 16 + l16) * 32 + q * 8]);
        #pragma unroll
        for (int t = 0; t < TN; ++t)
            bfr[t] = *reinterpret_cast<const short8*>(
                &Bs[(wn * TN * 16 + t * 16 + l16) * 32 + q * 8]);
        #pragma unroll
        for (int i = 0; i < TM; ++i)
            #pragma unroll
            for (int j = 0; j < TN; ++j)
                acc[i][j] = __builtin_amdgcn_mfma_f32_16x16x32_bf16(
                    af[i], bfr[j], acc[i][j], 0, 0, 0);
    }

    #pragma unroll
    for (int i = 0; i < TM; ++i) {
        #pragma unroll
        for (int j = 0; j < TN; ++j) {
            #pragma unroll
            for (int r = 0; r < 4; ++r) {
                int row = bm * BM + wm * TM * 16 + i * 16 + q * 4 + r;
                int col = bn * BN + wn * TN * 16 + j * 16 + l16;
                float v = acc[i][j][r];
                if constexpr (EPI == 0) {
                    Cb[(long)row * N + col] = f2bf(v * ep0[col]);
                } else if constexpr (EPI == 1) {
                    Cb[(long)row * N + col] = f2bf(v);
                } else if constexpr (EPI == 2) {
                    v += ep0[col];
                    v = v > 0.f ? v : 0.f;
                    Cb[(long)row * N + col] = f2bf(v);
                } else {
                    const int half = N >> 1;
                    if (col < half)
                        Cf[(long)row * half + col] = v + ep0[col];
                    else
                        Cf[(long)M * half + (long)row * half + (col - half)] = v + ep1[col - half];
                }
            }
        }
    }
}

extern "C" void kernel_launch(void* const* d_in, const int* in_sizes, int n_in,
                              void* d_out, int out_size, void* d_ws, size_t ws_size,
                              hipStream_t stream) {
    const float* x   = (const float*)d_in[0];
    const float* fw  = (const float*)d_in[1];
    const float* kp  = (const float*)d_in[2];
    const float* W1  = (const float*)d_in[3];
    const float* b1  = (const float*)d_in[4];
    const float* W2  = (const float*)d_in[5];
    const float* b2  = (const float*)d_in[6];
    const float* Wmu = (const float*)d_in[7];
    const float* bmu = (const float*)d_in[8];
    const float* Wlv = (const float*)d_in[9];
    const float* blv = (const float*)d_in[10];
    float* out = (float*)d_out;

    char* ws = (char*)d_ws;
    const size_t MB = 1024 * 1024;
    // Region reuse: [W1bf|Dbf|Dtbf|T1sT] (0..24MB) all dead before H1 (0..32MB) is written.
    ushort_t* W1bf = (ushort_t*)(ws + 0);        //  4 MB
    ushort_t* Dbf  = (ushort_t*)(ws + 4  * MB);  //  8 MB
    ushort_t* Dtbf = (ushort_t*)(ws + 12 * MB);  //  8 MB
    ushort_t* T1sT = (ushort_t*)(ws + 20 * MB);  //  4 MB
    ushort_t* H1   = (ushort_t*)(ws + 0);        // 32 MB (overlays the above)
    ushort_t* H2   = (ushort_t*)(ws + 32 * MB);  // 16 MB
    ushort_t* M1T  = (ushort_t*)(ws + 48 * MB);  //  4 MB
    ushort_t* W2bf = (ushort_t*)(ws + 52 * MB);  //  1 MB
    ushort_t* Wcat = (ushort_t*)(ws + 53 * MB);  // 0.5 MB
    float*    svec = (float*)   (ws + 54 * MB);  //  8 KB
    ushort_t* Xbf  = (ushort_t*)(ws + 55 * MB);  // 64 MB  (total 119 MB)

    hipLaunchKernelGGL(k_scale, dim3(DIM / 256), dim3(256), 0, stream, fw, kp, svec);
    hipLaunchKernelGGL(k_gen_d, dim3(DIM * DIM / 256), dim3(256), 0, stream, Dbf, Dtbf);

    hipLaunchKernelGGL(k_cast8, dim3(1024 * DIM / 8 / 256), dim3(256), 0, stream,
                       W1, W1bf, 1024 * DIM / 8);
    hipLaunchKernelGGL(k_cast8, dim3(512 * 1024 / 8 / 256), dim3(256), 0, stream,
                       W2, W2bf, 512 * 1024 / 8);
    hipLaunchKernelGGL(k_cast8, dim3(256 * 512 / 8 / 256), dim3(256), 0, stream,
                       Wmu, Wcat, 256 * 512 / 8);
    hipLaunchKernelGGL(k_cast8, dim3(256 * 512 / 8 / 256), dim3(256), 0, stream,
                       Wlv, Wcat + 256 * 512, 256 * 512 / 8);
    hipLaunchKernelGGL(k_cast8, dim3(BATCH * DIM / 8 / 256), dim3(256), 0, stream,
                       x, Xbf, BATCH * DIM / 8);

    // G0: T1sT[j][k] = s[k] * sum_n W1[j][n] * D[k][n]   (1024 x 2048, K=2048)
    hipLaunchKernelGGL((gemm_bt<2, 2, 0>), dim3((1024 / 64) * (2048 / 64)), dim3(256), 0, stream,
                       W1bf, Dbf, T1sT, nullptr, svec, nullptr, 1024, 2048, 2048);
    // G1: M1T[j][n] = sum_k T1sT[j][k] * Dt[n][k]        (1024 x 2048, K=2048)
    hipLaunchKernelGGL((gemm_bt<2, 2, 1>), dim3((1024 / 64) * (2048 / 64)), dim3(256), 0, stream,
                       T1sT, Dtbf, M1T, nullptr, nullptr, nullptr, 1024, 2048, 2048);
    // G2: H1 = relu(X @ M1 + b1)                          (16384 x 1024, K=2048)
    hipLaunchKernelGGL((gemm_bt<4, 4, 2>), dim3((BATCH / 128) * (1024 / 128)), dim3(256), 0, stream,
                       Xbf, M1T, H1, nullptr, b1, nullptr, BATCH, 1024, 2048);
    // G3: H2 = relu(H1 @ W2^T + b2)                       (16384 x 512, K=1024)
    hipLaunchKernelGGL((gemm_bt<4, 4, 2>), dim3((BATCH / 128) * (512 / 128)), dim3(256), 0, stream,
                       H1, W2bf, H2, nullptr, b2, nullptr, BATCH, 512, 1024);
    // G4: [mu | logvar] = H2 @ Wcat^T + bias, fp32 split output (16384 x 512, K=512)
    hipLaunchKernelGGL((gemm_bt<4, 4, 3>), dim3((BATCH / 128) * (512 / 128)), dim3(256), 0, stream,
                       H2, Wcat, nullptr, out, bmu, blv, BATCH, 512, 512);

    (void)in_sizes; (void)n_in; (void)out_size; (void)ws_size;
}

// Round 2
// 434.778 us; speedup vs baseline: 1.0571x; 1.0571x over previous
//
#include <hip/hip_runtime.h>
#include <hip/hip_bf16.h>
#include <math.h>

#define DIM 2048
#define BATCH 16384

typedef __attribute__((ext_vector_type(8))) short short8;
typedef __attribute__((ext_vector_type(4))) float floatx4;
typedef unsigned short ushort_t;

__device__ __forceinline__ ushort_t f2bf(float f) {
    union { float f; unsigned u; } v; v.f = f;
    unsigned r = v.u + 0x7FFFu + ((v.u >> 16) & 1u);   // RNE
    return (ushort_t)(r >> 16);
}

// ---- band scale vector (length DIM) ----
__global__ void k_scale(const float* __restrict__ fw, const float* __restrict__ kp,
                        float* __restrict__ s) {
    int n = blockIdx.x * blockDim.x + threadIdx.x;
    if (n >= DIM) return;
    float kv = kp[0];
    float f = 1.0f;
    for (int i = 0; i < 30; ++i) {
        long s0 = (long)((double)i       * (double)(DIM - 1) / 30.0);
        long e0 = (long)((double)(i + 1) * (double)(DIM - 1) / 30.0);
        if (n >= s0 && n < e0) {
            if (e0 <= 30)
                f = 1.0f + fw[i] * kv * (1.0f - (float)i / 30.0f);
            else
                f = 1.0f - fw[i] * kv * (1.0f - (float)(i - 30) / 30.0f);
        }
    }
    s[n] = f;
}

// ---- DCT matrix + transpose, bf16, exact integer phase reduction ----
__global__ void k_gen_d(ushort_t* __restrict__ D, ushort_t* __restrict__ Dt) {
    int idx = blockIdx.x * blockDim.x + threadIdx.x;   // DIM*DIM
    int r = idx >> 11;
    int c = idx & (DIM - 1);
    const float w  = 7.6699039394282058e-4f;  // pi/4096
    const float s0 = 0.02209708691207961f;    // sqrt(1/2048)
    const float s1 = 0.03125f;                // sqrt(2/2048)
    int m1 = ((2 * c + 1) * r) & (4 * DIM - 1);   // D[r][c]: cos(pi*(c+.5)*r/N)
    int m2 = ((2 * r + 1) * c) & (4 * DIM - 1);   // Dt[r][c] = D[c][r]
    float v1 = cosf(w * (float)m1) * (r == 0 ? s0 : s1);
    float v2 = cosf(w * (float)m2) * (c == 0 ? s0 : s1);
    D[idx]  = f2bf(v1);
    Dt[idx] = f2bf(v2);
}

// ---- merged fp32 -> bf16 cast for all tensors, 8 elems/thread ----
// unit ranges (8-elem units): X:4194304 | W1:262144 | W2:65536 | Wmu:16384 | Wlv:16384
#define U_X   4194304
#define U_W1   262144
#define U_W2    65536
#define U_WH    16384
__global__ void k_cast_all(const float* __restrict__ X,  const float* __restrict__ W1,
                           const float* __restrict__ W2, const float* __restrict__ Wmu,
                           const float* __restrict__ Wlv,
                           ushort_t* __restrict__ Xbf, ushort_t* __restrict__ W1bf,
                           ushort_t* __restrict__ W2bf, ushort_t* __restrict__ Wcat) {
    int i = blockIdx.x * blockDim.x + threadIdx.x;
    const float* src; ushort_t* dst; int u;
    if (i < U_X)                          { src = X;   dst = Xbf;                u = i; }
    else if (i < U_X + U_W1)              { src = W1;  dst = W1bf;               u = i - U_X; }
    else if (i < U_X + U_W1 + U_W2)       { src = W2;  dst = W2bf;               u = i - U_X - U_W1; }
    else if (i < U_X + U_W1 + U_W2 + U_WH){ src = Wmu; dst = Wcat;               u = i - U_X - U_W1 - U_W2; }
    else                                  { src = Wlv; dst = Wcat + 8 * U_WH;    u = i - U_X - U_W1 - U_W2 - U_WH; }
    const float4* p = reinterpret_cast<const float4*>(src) + 2 * (size_t)u;
    float4 a = p[0], b = p[1];
    short8 r;
    r[0] = (short)f2bf(a.x); r[1] = (short)f2bf(a.y);
    r[2] = (short)f2bf(a.z); r[3] = (short)f2bf(a.w);
    r[4] = (short)f2bf(b.x); r[5] = (short)f2bf(b.y);
    r[6] = (short)f2bf(b.z); r[7] = (short)f2bf(b.w);
    *reinterpret_cast<short8*>(dst + 8 * (size_t)u) = r;
}

// ---- C = A @ B^T, A: MxK bf16 row-major, B: NxK bf16 row-major (m97 structure) ----
// LDS layout: slot (row, t) holds global segment t ^ ((row>>1)&3) of that row's
// 32-wide K slice (XOR applied on GLOBAL address since global_load_lds's LDS
// destination is forced to base + lane*16). Reads un-permute with the same XOR.
// Block mapping: xcd = bid&7 owns a contiguous band of bm rows (L2 locality).
// EPI 0: *ep0[col] -> bf16 | 1: plain -> bf16 | 2: +ep0[col], relu -> bf16
// EPI 3: +bias (ep0 cols<N/2, ep1 cols>=N/2) -> fp32 split output (mu | logvar)
template<int TM, int TN, int EPI>
__global__ __launch_bounds__(256)
void gemm_bt(const ushort_t* __restrict__ A, const ushort_t* __restrict__ B,
             ushort_t* __restrict__ Cb, float* __restrict__ Cf,
             const float* __restrict__ ep0, const float* __restrict__ ep1,
             int M, int N, int K) {
    constexpr int BM = 32 * TM;
    constexpr int BN = 32 * TN;
    __shared__ __align__(16) ushort_t As[BM * 32];
    __shared__ __align__(16) ushort_t Bs[BN * 32];

    const int tid  = threadIdx.x;
    const int lane = tid & 63;
    const int wave = tid >> 6;
    const int wm   = wave >> 1;
    const int wn   = wave & 1;
    const int q    = lane >> 4;
    const int l16  = lane & 15;

    // XCD-aware block mapping (grid = tilesM*tilesN, both tilesM%8==0 cases hold)
    const int tilesM = M / BM;
    const int tilesN = N / BN;
    const int bid = (int)blockIdx.x;
    const int xcd = bid & 7;
    const int j   = bid >> 3;
    const int bm  = xcd * (tilesM >> 3) + j / tilesN;
    const int bn  = j % tilesN;

    floatx4 acc[TM][TN];
    #pragma unroll
    for (int i = 0; i < TM; ++i)
        #pragma unroll
        for (int jj = 0; jj < TN; ++jj)
            acc[i][jj] = (floatx4){0.f, 0.f, 0.f, 0.f};

    const long aBase = (long)bm * BM * K;
    const long bBase = (long)bn * BN * K;

    for (int kt = 0; kt < K; kt += 32) {
        __syncthreads();
        #pragma unroll
        for (int i = 0; i < BM / 64; ++i) {
            int idx = tid + i * 256;
            int row = idx >> 2, seg = idx & 3;
            int gseg = seg ^ ((row >> 1) & 3);
            const ushort_t* g = A + aBase + (long)row * K + kt + gseg * 8;
            __builtin_amdgcn_global_load_lds(
                (const __attribute__((address_space(1))) void*)g,
                (__attribute__((address_space(3))) void*)(As + idx * 8),
                16, 0, 0);
        }
        #pragma unroll
        for (int i = 0; i < BN / 64; ++i) {
            int idx = tid + i * 256;
            int row = idx >> 2, seg = idx & 3;
            int gseg = seg ^ ((row >> 1) & 3);
            const ushort_t* g = B + bBase + (long)row * K + kt + gseg * 8;
            __builtin_amdgcn_global_load_lds(
                (const __attribute__((address_space(1))) void*)g,
                (__attribute__((address_space(3))) void*)(Bs + idx * 8),
                16, 0, 0);
        }
        __syncthreads();

        short8 af[TM], bfr[TN];
        #pragma unroll
        for (int t = 0; t < TM; ++t) {
            int srow = wm * TM * 16 + t * 16 + l16;
            int rseg = q ^ ((srow >> 1) & 3);
            af[t] = *reinterpret_cast<const short8*>(&As[srow * 32 + rseg * 8]);
        }
        #pragma unroll
        for (int t = 0; t < TN; ++t) {
            int srow = wn * TN * 16 + t * 16 + l16;
            int rseg = q ^ ((srow >> 1) & 3);
            bfr[t] = *reinterpret_cast<const short8*>(&Bs[srow * 32 + rseg * 8]);
        }
        #pragma unroll
        for (int i = 0; i < TM; ++i)
            #pragma unroll
            for (int jj = 0; jj < TN; ++jj)
                acc[i][jj] = __builtin_amdgcn_mfma_f32_16x16x32_bf16(
                    af[i], bfr[jj], acc[i][jj], 0, 0, 0);
    }

    #pragma unroll
    for (int i = 0; i < TM; ++i) {
        #pragma unroll
        for (int jj = 0; jj < TN; ++jj) {
            #pragma unroll
            for (int r = 0; r < 4; ++r) {
                int row = bm * BM + wm * TM * 16 + i * 16 + q * 4 + r;
                int col = bn * BN + wn * TN * 16 + jj * 16 + l16;
                float v = acc[i][jj][r];
                if constexpr (EPI == 0) {
                    Cb[(long)row * N + col] = f2bf(v * ep0[col]);
                } else if constexpr (EPI == 1) {
                    Cb[(long)row * N + col] = f2bf(v);
                } else if constexpr (EPI == 2) {
                    v += ep0[col];
                    v = v > 0.f ? v : 0.f;
                    Cb[(long)row * N + col] = f2bf(v);
                } else {
                    const int half = N >> 1;
                    if (col < half)
                        Cf[(long)row * half + col] = v + ep0[col];
                    else
                        Cf[(long)M * half + (long)row * half + (col - half)] = v + ep1[col - half];
                }
            }
        }
    }
}

extern "C" void kernel_launch(void* const* d_in, const int* in_sizes, int n_in,
                              void* d_out, int out_size, void* d_ws, size_t ws_size,
                              hipStream_t stream) {
    const float* x   = (const float*)d_in[0];
    const float* fw  = (const float*)d_in[1];
    const float* kp  = (const float*)d_in[2];
    const float* W1  = (const float*)d_in[3];
    const float* b1  = (const float*)d_in[4];
    const float* W2  = (const float*)d_in[5];
    const float* b2  = (const float*)d_in[6];
    const float* Wmu = (const float*)d_in[7];
    const float* bmu = (const float*)d_in[8];
    const float* Wlv = (const float*)d_in[9];
    const float* blv = (const float*)d_in[10];
    float* out = (float*)d_out;

    char* ws = (char*)d_ws;
    const size_t MB = 1024 * 1024;
    // Region reuse: [W1bf|Dbf|Dtbf|T1sT] (0..24MB) all dead before H1 (0..32MB) is written.
    ushort_t* W1bf = (ushort_t*)(ws + 0);        //  4 MB
    ushort_t* Dbf  = (ushort_t*)(ws + 4  * MB);  //  8 MB
    ushort_t* Dtbf = (ushort_t*)(ws + 12 * MB);  //  8 MB
    ushort_t* T1sT = (ushort_t*)(ws + 20 * MB);  //  4 MB
    ushort_t* H1   = (ushort_t*)(ws + 0);        // 32 MB (overlays the above)
    ushort_t* H2   = (ushort_t*)(ws + 32 * MB);  // 16 MB
    ushort_t* M1T  = (ushort_t*)(ws + 48 * MB);  //  4 MB
    ushort_t* W2bf = (ushort_t*)(ws + 52 * MB);  //  1 MB
    ushort_t* Wcat = (ushort_t*)(ws + 53 * MB);  // 0.5 MB
    float*    svec = (float*)   (ws + 54 * MB);  //  8 KB
    ushort_t* Xbf  = (ushort_t*)(ws + 55 * MB);  // 64 MB  (total 119 MB)

    hipLaunchKernelGGL(k_scale, dim3(DIM / 256), dim3(256), 0, stream, fw, kp, svec);
    hipLaunchKernelGGL(k_gen_d, dim3(DIM * DIM / 256), dim3(256), 0, stream, Dbf, Dtbf);

    // one merged cast: X + W1 + W2 + Wmu + Wlv  (4554752 units / 256 = 17792 blocks)
    hipLaunchKernelGGL(k_cast_all, dim3((U_X + U_W1 + U_W2 + 2 * U_WH) / 256), dim3(256), 0, stream,
                       x, W1, W2, Wmu, Wlv, Xbf, W1bf, W2bf, Wcat);

    // G0: T1sT[j][k] = s[k] * sum_n W1[j][n] * D[k][n]   (1024 x 2048, K=2048)
    hipLaunchKernelGGL((gemm_bt<2, 2, 0>), dim3((1024 / 64) * (2048 / 64)), dim3(256), 0, stream,
                       W1bf, Dbf, T1sT, nullptr, svec, nullptr, 1024, 2048, 2048);
    // G1: M1T[j][n] = sum_k T1sT[j][k] * Dt[n][k]        (1024 x 2048, K=2048)
    hipLaunchKernelGGL((gemm_bt<2, 2, 1>), dim3((1024 / 64) * (2048 / 64)), dim3(256), 0, stream,
                       T1sT, Dtbf, M1T, nullptr, nullptr, nullptr, 1024, 2048, 2048);
    // G2: H1 = relu(X @ M1 + b1)                          (16384 x 1024, K=2048)
    hipLaunchKernelGGL((gemm_bt<4, 4, 2>), dim3((BATCH / 128) * (1024 / 128)), dim3(256), 0, stream,
                       Xbf, M1T, H1, nullptr, b1, nullptr, BATCH, 1024, 2048);
    // G3: H2 = relu(H1 @ W2^T + b2)                       (16384 x 512, K=1024)
    hipLaunchKernelGGL((gemm_bt<4, 4, 2>), dim3((BATCH / 128) * (512 / 128)), dim3(256), 0, stream,
                       H1, W2bf, H2, nullptr, b2, nullptr, BATCH, 512, 1024);
    // G4: [mu | logvar] = H2 @ Wcat^T + bias, fp32 split output (16384 x 512, K=512)
    hipLaunchKernelGGL((gemm_bt<4, 4, 3>), dim3((BATCH / 128) * (512 / 128)), dim3(256), 0, stream,
                       H2, Wcat, nullptr, out, bmu, blv, BATCH, 512, 512);

    (void)in_sizes; (void)n_in; (void)out_size; (void)ws_size;
}